// Round 6
// baseline (61.936 us; speedup 1.0000x reference)
//
#include <hip/hip_runtime.h>

#define EPSF 1e-6f
#define TPB 256
#define KMAXC 21           // seg channels staged (K = 21)
#define NGR 21             // gt rows staged
#define RB 264             // bf16 row stride: 528 B = 33*16 (aligned frags, good bank spread)
#define TBL 1024           // 32x32 cells per replica table
#define NREP 4             // replicated atomic tables
#define CNT_OFF (TBL * NREP)   // float index of int counter in d_ws

typedef float  f32x4  __attribute__((ext_vector_type(4)));
typedef float  f32x16 __attribute__((ext_vector_type(16)));
typedef __bf16 bf16x8 __attribute__((ext_vector_type(8)));

// A[k,g] = sum_n d[k,n]*gi[g,n], d = log2((s+eps)/(1-s+eps)) in bf16;
// argmin_g ce[k,g] == argmax_g A[k,g] (ce = -(A*ln2 + const_k)/N).
// One 32x32 MFMA tile covers all (k,g); K-dim = pixels.
__global__ __launch_bounds__(TPB, 4) void msk_mfma(
    const float* __restrict__ seg,   // (N, K) row-major
    const int* __restrict__ gt,      // (GROWS, N) row-major
    const int* __restrict__ gpn,     // scalar gt_plane_num
    float* __restrict__ sums,        // d_ws: NREP*[TBL] floats + counter
    int* __restrict__ out,           // (K,) int32
    int N, int K, int GROWS, int NT, int NBLK)
{
    const int G = *gpn;
    const int tid  = threadIdx.x;
    const int lane = tid & 63;
    const int wv   = tid >> 6;

    __shared__ union {
        struct { __bf16 d[KMAXC * RB]; __bf16 m[NGR * RB]; } s;  // 22176 B
        float red[4 * TBL];                                      // 16384 B
    } u;
    __shared__ int last_flag;

    f32x16 acc = {};   // per-wave 32x32 fp32 accumulator (16 regs)

    const unsigned lowmask = (G >= 32) ? 0xFFFFFFFFu
                                       : ((G <= 0) ? 0u : ((1u << G) - 1u));

    for (int tile = blockIdx.x; tile < NT; tile += NBLK) {
        const int pix0 = tile * TPB;
        __syncthreads();   // previous tile's fragment reads complete

        // ---- stage seg: coalesced f32x4 loads, log-odds, bf16 scatter [k][pix] ----
        if (pix0 + TPB <= N) {
            const f32x4* src = (const f32x4*)(seg + (size_t)pix0 * K);
            const int TE4 = (TPB * K) >> 2;          // 1344 (K=21)
            for (int i4 = tid; i4 < TE4; i4 += TPB) {
                const f32x4 v = src[i4];
                const int lin = i4 << 2;
                int pix = lin / K;                   // magic-div
                int k   = lin - pix * K;
                #pragma unroll
                for (int c = 0; c < 4; ++c) {
                    const float s = v[c];
                    const float dd = __log2f(s + EPSF) - __log2f(1.0f - s + EPSF);
                    u.s.d[k * RB + pix] = (__bf16)dd;
                    if (++k == K) { k = 0; ++pix; }  // branchless wrap
                }
            }
        } else {
            for (int i = tid; i < TPB * K; i += TPB) {
                const int pix = i / K, k = i - pix * K;
                const float s = (pix0 + pix < N) ? seg[(size_t)pix0 * K + i] : 0.5f;
                const float dd = __log2f(s + EPSF) - __log2f(1.0f - s + EPSF);
                u.s.d[k * RB + pix] = (__bf16)dd;    // s=0.5 -> d=0 (inert)
            }
        }

        // ---- stage gt: 21 independent coalesced loads -> bf16 0/1 rows [g][pix] ----
        {
            const int p = pix0 + tid;
            unsigned mbits = 0u;
            if (p < N) {
                #pragma unroll
                for (int g = 0; g < NGR; ++g) {
                    const int gg = (g < GROWS) ? g : (GROWS - 1);
                    mbits |= (gt[(size_t)gg * N + p] != 0) ? (1u << g) : 0u;
                }
                mbits &= lowmask;
            }
            #pragma unroll
            for (int g = 0; g < NGR; ++g)
                u.s.m[g * RB + tid] = (__bf16)(float)((mbits >> g) & 1u);
        }
        __syncthreads();

        // ---- MFMA: wave wv covers pixels [wv*64, wv*64+64), 4x K=16 steps ----
        {
            const int r31  = lane & 31;
            const int rowA = (r31 < K)   ? r31 : (K - 1);     // clamp: dup rows discarded
            const int rowB = (r31 < NGR) ? r31 : (NGR - 1);
            const int off  = wv * 64 + ((lane >> 5) << 3);
            const __bf16* pa = &u.s.d[rowA * RB + off];
            const __bf16* pb = &u.s.m[rowB * RB + off];
            #pragma unroll
            for (int i = 0; i < 4; ++i) {
                const bf16x8 af = *(const bf16x8*)(pa + i * 16);
                const bf16x8 bf = *(const bf16x8*)(pb + i * 16);
                acc = __builtin_amdgcn_mfma_f32_32x32x16_bf16(af, bf, acc, 0, 0, 0);
            }
        }
    }

    // ---- cross-wave reduce via canonical LDS layout ----
    __syncthreads();
    {
        const int col = lane & 31;
        const int rhi = (lane >> 5) << 2;
        #pragma unroll
        for (int r = 0; r < 16; ++r) {
            const int row = (r & 3) + ((r >> 2) << 3) + rhi;   // verified C/D mapping
            u.red[wv * TBL + row * 32 + col] = acc[r];
        }
    }
    __syncthreads();

    // ---- atomic combine (live cells only), device-scope ----
    {
        float* stbl = sums + (size_t)(blockIdx.x & (NREP - 1)) * TBL;
        #pragma unroll
        for (int q = 0; q < TBL / TPB; ++q) {
            const int cell = q * TPB + tid;
            const float v = u.red[cell] + u.red[TBL + cell]
                          + u.red[2 * TBL + cell] + u.red[3 * TBL + cell];
            const int row = cell >> 5, col = cell & 31;
            if (row < K && col < G) atomicAdd(&stbl[cell], v);
        }
    }
    __syncthreads();   // drains vmcnt -> atomics globally performed

    int* cnt = (int*)(sums + CNT_OFF);
    if (tid == 0) {
        const int done = __hip_atomic_fetch_add(cnt, 1, __ATOMIC_ACQ_REL,
                                                __HIP_MEMORY_SCOPE_AGENT);
        last_flag = (done == NBLK - 1) ? 1 : 0;
    }
    __syncthreads();
    if (!last_flag) return;

    // ---- last block: sum replicas, first-index argmax per k row ----
    for (int cell = tid; cell < TBL; cell += TPB) {
        float v = 0.f;
        #pragma unroll
        for (int r = 0; r < NREP; ++r)
            v += __hip_atomic_load(&sums[(size_t)r * TBL + cell], __ATOMIC_ACQUIRE,
                                   __HIP_MEMORY_SCOPE_AGENT);
        u.red[cell] = v;
    }
    __syncthreads();

    if (tid < K) {
        const int GG = (G < 32) ? G : 32;
        float bv; int bg = 0;
        if (GG > 0) {
            bv = u.red[tid * 32];
            for (int g = 1; g < GG; ++g) {
                const float v = u.red[tid * 32 + g];
                if (v > bv) { bv = v; bg = g; }   // strict '>' keeps first index
            }
        }
        out[tid] = bg;
    }
}

extern "C" void kernel_launch(void* const* d_in, const int* in_sizes, int n_in,
                              void* d_out, int out_size, void* d_ws, size_t ws_size,
                              hipStream_t stream) {
    const float* seg = (const float*)d_in[0];
    // d_in[1] (prob) does not affect the reference output
    const int* gt  = (const int*)d_in[2];
    const int* gpn = (const int*)d_in[3];

    const int N = in_sizes[1];              // prob is (N,1)
    const int K = in_sizes[0] / N;          // 21
    const int GROWS = in_sizes[2] / N;      // 21
    const int NT = (N + TPB - 1) / TPB;     // 1200

    int NBLK = NT;                          // 1 tile per block, all co-resident
    if (NBLK > 2048) NBLK = 2048;
    if (NBLK < 1) NBLK = 1;

    // zero replica tables + counter every call (16.4 KB of d_ws)
    hipMemsetAsync(d_ws, 0, CNT_OFF * sizeof(float) + 16, stream);

    msk_mfma<<<NBLK, TPB, 0, stream>>>(seg, gt, gpn, (float*)d_ws, (int*)d_out,
                                       N, K, GROWS, NT, NBLK);
}

// Round 7
// 58.044 us; speedup vs baseline: 1.0670x; 1.0670x over previous
//
#include <hip/hip_runtime.h>

#define EPSF 1e-6f
#define TPB 256
#define KMAXC 21           // seg channels staged (K = 21)
#define NGR 21             // gt rows staged
#define RB 264             // bf16 row stride: 528 B (16B-aligned frags)
#define TBL 1024           // 32x32 cells per replica table
#define NREP 8             // replicated atomic tables
#define SUMS_FLOATS (NREP * TBL)   // 8192 floats = 32 KB
#define NGRP 32            // first-level counter fanout

typedef float  f32x4  __attribute__((ext_vector_type(4)));
typedef float  f32x16 __attribute__((ext_vector_type(16)));
typedef __bf16 bf16x8 __attribute__((ext_vector_type(8)));

// A[k,g] = sum_n d[k,n]*gi[g,n], d = log2((s+eps)/(1-s+eps)) in bf16;
// argmin_g ce[k,g] == argmax_g A[k,g] (ce = -(A*ln2 + const_k)/N).
__global__ __launch_bounds__(TPB) void msk_mfma(
    const float* __restrict__ seg,   // (N, K) row-major
    const int* __restrict__ gt,      // (GROWS, N) row-major
    const int* __restrict__ gpn,     // scalar gt_plane_num
    float* __restrict__ sums,        // d_ws: NREP*[TBL] f32, int cnt1[NGRP], int cnt2
    int* __restrict__ out,           // (K,) int32
    int N, int K, int GROWS, int NT, int NBLK)
{
    const int G = *gpn;
    const int tid  = threadIdx.x;
    const int lane = tid & 63;
    const int wv   = tid >> 6;

    __shared__ union {
        struct { __bf16 d[KMAXC * RB]; __bf16 m[NGR * RB]; } s;  // 22176 B
        float red[4 * TBL];                                      // 16384 B
    } u;
    __shared__ int last_flag;

    f32x16 acc = {};   // per-wave 32x32 fp32 accumulator

    for (int tile = blockIdx.x; tile < NT; tile += NBLK) {
        const int pix0 = tile * TPB;
        __syncthreads();   // previous tile's fragment reads complete

        if (K == KMAXC && pix0 + TPB <= N) {
            // ---- burst: 12 predicated x4 loads back-to-back, one waitcnt ----
            const int TE4 = (TPB * KMAXC) >> 2;          // 1344
            f32x4 sreg[6];
            int4  greg[6];
            const f32x4* s4 = (const f32x4*)(seg + (size_t)pix0 * KMAXC);
            #pragma unroll
            for (int q = 0; q < 6; ++q) {
                const int i4 = tid + q * TPB;
                f32x4 v = {0.5f, 0.5f, 0.5f, 0.5f};
                if (i4 < TE4) v = s4[i4];
                sreg[q] = v;
            }
            #pragma unroll
            for (int q = 0; q < 6; ++q) {
                const int i4 = tid + q * TPB;
                int4 gv = {0, 0, 0, 0};
                if (i4 < TE4) {
                    int row = i4 >> 6;                   // 0..20 (wave-uniform)
                    row = (row < GROWS) ? row : (GROWS - 1);
                    gv = *(const int4*)(gt + (size_t)row * N + pix0 + ((i4 & 63) << 2));
                }
                greg[q] = gv;
            }
            // ---- convert + LDS scatter ----
            #pragma unroll
            for (int q = 0; q < 6; ++q) {
                const int i4 = tid + q * TPB;
                if (i4 < TE4) {
                    const int lin = i4 << 2;
                    int pix = lin / KMAXC;
                    int k   = lin - pix * KMAXC;
                    #pragma unroll
                    for (int c = 0; c < 4; ++c) {
                        const float s = sreg[q][c];
                        const float dd = __log2f(s + EPSF) - __log2f(1.0f - s + EPSF);
                        u.s.d[k * RB + pix] = (__bf16)dd;
                        if (++k == KMAXC) { k = 0; ++pix; }
                    }
                    const int row  = i4 >> 6;
                    __bf16* mp = &u.s.m[row * RB + ((i4 & 63) << 2)];
                    mp[0] = (__bf16)(float)(greg[q].x != 0);
                    mp[1] = (__bf16)(float)(greg[q].y != 0);
                    mp[2] = (__bf16)(float)(greg[q].z != 0);
                    mp[3] = (__bf16)(float)(greg[q].w != 0);
                }
            }
        } else {
            // ---- generic fallback (tail tile / odd K) ----
            for (int i = tid; i < TPB * K; i += TPB) {
                const int pix = i / K, k = i - pix * K;
                const float s = (pix0 + pix < N) ? seg[(size_t)pix0 * K + i] : 0.5f;
                const float dd = __log2f(s + EPSF) - __log2f(1.0f - s + EPSF);
                if (k < KMAXC) u.s.d[k * RB + pix] = (__bf16)dd;   // 0.5 -> d=0 (inert)
            }
            const int p = pix0 + tid;
            #pragma unroll
            for (int g = 0; g < NGR; ++g) {
                const int gg = (g < GROWS) ? g : (GROWS - 1);
                int val = 0;
                if (p < N) val = (gt[(size_t)gg * N + p] != 0);
                u.s.m[g * RB + tid] = (__bf16)(float)val;
            }
        }
        __syncthreads();

        // ---- MFMA: wave wv covers pixels [wv*64, wv*64+64), 4x K=16 steps ----
        {
            const int r31  = lane & 31;
            const int rowA = (r31 < K)   ? r31 : (K - 1);   // clamp: dup rows discarded
            const int rowB = (r31 < NGR) ? r31 : (NGR - 1);
            const int off  = wv * 64 + ((lane >> 5) << 3);
            const __bf16* pa = &u.s.d[rowA * RB + off];
            const __bf16* pb = &u.s.m[rowB * RB + off];
            #pragma unroll
            for (int i = 0; i < 4; ++i) {
                const bf16x8 af = *(const bf16x8*)(pa + i * 16);
                const bf16x8 bf = *(const bf16x8*)(pb + i * 16);
                acc = __builtin_amdgcn_mfma_f32_32x32x16_bf16(af, bf, acc, 0, 0, 0);
            }
        }
    }

    // ---- cross-wave reduce via canonical LDS layout ----
    __syncthreads();
    {
        const int col = lane & 31;
        const int rhi = (lane >> 5) << 2;
        #pragma unroll
        for (int r = 0; r < 16; ++r) {
            const int row = (r & 3) + ((r >> 2) << 3) + rhi;   // verified C/D mapping
            u.red[wv * TBL + row * 32 + col] = acc[r];
        }
    }
    __syncthreads();

    // ---- atomic combine (live cells only), device-scope, XCD-local replica ----
    {
        float* stbl = sums + (size_t)(blockIdx.x & (NREP - 1)) * TBL;
        #pragma unroll
        for (int q = 0; q < TBL / TPB; ++q) {
            const int cell = q * TPB + tid;
            const float v = u.red[cell] + u.red[TBL + cell]
                          + u.red[2 * TBL + cell] + u.red[3 * TBL + cell];
            const int row = cell >> 5, col = cell & 31;
            if (row < K && col < G) atomicAdd(&stbl[cell], v);
        }
    }
    __syncthreads();   // drains vmcnt -> this block's atomics globally performed

    // ---- hierarchical done-counter: chains of ~38, then 32 ----
    int* cnt1 = (int*)(sums + SUMS_FLOATS);
    int* cnt2 = cnt1 + NGRP;
    if (tid == 0) {
        last_flag = 0;
        const int grp = (int)blockIdx.x & (NGRP - 1);
        const int quota = NBLK / NGRP + (((NBLK % NGRP) > grp) ? 1 : 0);
        const int dg = __hip_atomic_fetch_add(&cnt1[grp], 1, __ATOMIC_ACQ_REL,
                                              __HIP_MEMORY_SCOPE_AGENT);
        if (dg == quota - 1) {
            const int live = (NBLK < NGRP) ? NBLK : NGRP;
            const int d2 = __hip_atomic_fetch_add(cnt2, 1, __ATOMIC_ACQ_REL,
                                                  __HIP_MEMORY_SCOPE_AGENT);
            if (d2 == live - 1) last_flag = 1;
        }
    }
    __syncthreads();
    if (!last_flag) return;

    // ---- last block: sum replicas, first-index argmax per k row ----
    for (int cell = tid; cell < TBL; cell += TPB) {
        float v = 0.f;
        #pragma unroll
        for (int r = 0; r < NREP; ++r)
            v += __hip_atomic_load(&sums[(size_t)r * TBL + cell], __ATOMIC_ACQUIRE,
                                   __HIP_MEMORY_SCOPE_AGENT);
        u.red[cell] = v;
    }
    __syncthreads();

    if (tid < K) {
        const int GG = (G < 32) ? G : 32;
        float bv; int bg = 0;
        if (GG > 0) {
            bv = u.red[tid * 32];
            for (int g = 1; g < GG; ++g) {
                const float v = u.red[tid * 32 + g];
                if (v > bv) { bv = v; bg = g; }   // strict '>' keeps first index
            }
        }
        out[tid] = bg;
    }
}

extern "C" void kernel_launch(void* const* d_in, const int* in_sizes, int n_in,
                              void* d_out, int out_size, void* d_ws, size_t ws_size,
                              hipStream_t stream) {
    const float* seg = (const float*)d_in[0];
    // d_in[1] (prob) does not affect the reference output
    const int* gt  = (const int*)d_in[2];
    const int* gpn = (const int*)d_in[3];

    const int N = in_sizes[1];              // prob is (N,1)
    const int K = in_sizes[0] / N;          // 21
    const int GROWS = in_sizes[2] / N;      // 21
    const int NT = (N + TPB - 1) / TPB;     // 1200

    int NBLK = NT;                          // 1 tile per block
    if (NBLK > 4096) NBLK = 4096;
    if (NBLK < 1) NBLK = 1;

    // zero replica tables + both counter levels every call (33 KB of d_ws)
    hipMemsetAsync(d_ws, 0, SUMS_FLOATS * sizeof(float) + (NGRP + 1) * sizeof(int),
                   stream);

    msk_mfma<<<NBLK, TPB, 0, stream>>>(seg, gt, gpn, (float*)d_ws, (int*)d_out,
                                       N, K, GROWS, NT, NBLK);
}

// Round 8
// 37.888 us; speedup vs baseline: 1.6347x; 1.5320x over previous
//
#include <hip/hip_runtime.h>

#define EPSF 1e-6f
#define TPB 256
#define KMAXC 21           // seg channels (K = 21)
#define NGR 21             // gt rows staged
#define RW 72              // bf16 row stride per wave slice (144 B; 16B-aligned frags)
#define SLICE (KMAXC * RW) // 1512 bf16 per matrix per wave
#define TBL 1024           // 32x32 cells per replica table
#define NREP 8             // replicated atomic tables
#define SUMS_FLOATS (NREP * TBL)   // 8192 floats = 32 KB

typedef float  f32x4  __attribute__((ext_vector_type(4)));
typedef float  f32x16 __attribute__((ext_vector_type(16)));
typedef __bf16 bf16x8 __attribute__((ext_vector_type(8)));
typedef __bf16 bf16x4 __attribute__((ext_vector_type(4)));

// A[k,g] = sum_n d[k,n]*gi[g,n], d = log2((s+eps)/(1-s+eps)) in bf16;
// argmin_g ce[k,g] == argmax_g A[k,g] (ce = -(A*ln2 + const_k)/N).
// Wave-private: each wave streams 64-pixel groups with no intra-loop barriers.
__global__ __launch_bounds__(TPB) void msk_wave(
    const float* __restrict__ seg,   // (N, K) row-major
    const int* __restrict__ gt,      // (GROWS, N) row-major
    const int* __restrict__ gpn,     // scalar gt_plane_num
    float* __restrict__ sums,        // d_ws: NREP*[TBL] f32 + int counter
    int* __restrict__ out,           // (K,) int32
    int N, int K, int GROWS, int NGROUP, int NBLK)
{
    const int G = *gpn;
    const int tid  = threadIdx.x;
    const int lane = tid & 63;
    const int wv   = tid >> 6;

    __shared__ union {
        __bf16 stage[4][2][SLICE];   // [wave][0=d rows [k][px], 1=mask rows [g][px]]
        float  red[4 * TBL];
    } u;
    __shared__ int last_flag;

    f32x16 acc = {};                 // per-wave 32x32 fp32 accumulator

    __bf16* dl = u.stage[wv][0];
    __bf16* ml = u.stage[wv][1];

    const int W  = NBLK * 4;         // total waves
    const int gw = (int)blockIdx.x * 4 + wv;

    for (int gid = gw; gid < NGROUP; gid += W) {
        const int p0 = gid << 6;     // first pixel of this 64-px group

        if (K == KMAXC && p0 + 64 <= N) {
            // ---- burst: 6 seg f32x4 + 6 gt int4, all in flight ----
            f32x4 sreg[6]; int4 greg[6];
            const f32x4* s4 = (const f32x4*)(seg + (size_t)p0 * KMAXC);
            #pragma unroll
            for (int q = 0; q < 6; ++q) {
                const int i4 = lane + (q << 6);            // f32x4 idx in [0,336)
                f32x4 v = {0.5f, 0.5f, 0.5f, 0.5f};
                if (i4 < 336) v = s4[i4];
                sreg[q] = v;
            }
            #pragma unroll
            for (int q = 0; q < 6; ++q) {
                const int i4 = lane + (q << 6);
                int4 gv = {0, 0, 0, 0};
                if (i4 < 336) {
                    int row = i4 >> 4;                     // 0..20 (16 int4 per row)
                    row = (row < GROWS) ? row : (GROWS - 1);
                    gv = *(const int4*)(gt + (size_t)row * N + p0 + ((i4 & 15) << 2));
                }
                greg[q] = gv;
            }
            // ---- scatter d (log-odds, bf16) ----
            #pragma unroll
            for (int q = 0; q < 6; ++q) {
                const int i4 = lane + (q << 6);
                if (i4 < 336) {
                    const int lin = i4 << 2;
                    int pix = lin / KMAXC;
                    int k   = lin - pix * KMAXC;
                    #pragma unroll
                    for (int c = 0; c < 4; ++c) {
                        const float s = sreg[q][c];
                        const float dd = __log2f(s + EPSF) - __log2f(1.0f - s + EPSF);
                        dl[k * RW + pix] = (__bf16)dd;
                        if (++k == KMAXC) { k = 0; ++pix; }
                    }
                }
            }
            // ---- scatter mask rows (bf16 0/1, b64 writes) ----
            #pragma unroll
            for (int q = 0; q < 6; ++q) {
                const int i4 = lane + (q << 6);
                if (i4 < 336) {
                    const int row = i4 >> 4;
                    bf16x4 mv;
                    mv[0] = (__bf16)(float)(greg[q].x != 0);
                    mv[1] = (__bf16)(float)(greg[q].y != 0);
                    mv[2] = (__bf16)(float)(greg[q].z != 0);
                    mv[3] = (__bf16)(float)(greg[q].w != 0);
                    *(bf16x4*)(ml + row * RW + ((i4 & 15) << 2)) = mv;
                }
            }
        } else {
            // ---- generic fallback (tail group / odd K) ----
            for (int i = lane; i < K * 64; i += 64) {
                const int pix = i / K, k = i - pix * K;
                const float s = (p0 + pix < N) ? seg[(size_t)(p0 + pix) * K + k] : 0.5f;
                const float dd = __log2f(s + EPSF) - __log2f(1.0f - s + EPSF);
                if (k < KMAXC) dl[k * RW + pix] = (__bf16)dd;   // s=0.5 -> d=0 (inert)
            }
            for (int i = lane; i < NGR * 64; i += 64) {
                const int row = i >> 6, c = i & 63;
                int val = 0;
                if (row < GROWS && p0 + c < N) val = (gt[(size_t)row * N + p0 + c] != 0);
                ml[row * RW + c] = (__bf16)(float)val;
            }
        }
        // (within-wave LDS ordering: writes complete before dependent reads)

        // ---- 4x MFMA over the 64-px group (K-dim = pixels) ----
        {
            const int r31  = lane & 31;
            const int rowA = (r31 < K)   ? r31 : (K - 1);   // clamp: dup rows discarded
            const int rowB = (r31 < NGR) ? r31 : (NGR - 1);
            const int off  = (lane >> 5) << 3;
            const __bf16* pa = dl + rowA * RW + off;
            const __bf16* pb = ml + rowB * RW + off;
            #pragma unroll
            for (int i = 0; i < 4; ++i) {
                const bf16x8 af = *(const bf16x8*)(pa + i * 16);
                const bf16x8 bf = *(const bf16x8*)(pb + i * 16);
                acc = __builtin_amdgcn_mfma_f32_32x32x16_bf16(af, bf, acc, 0, 0, 0);
            }
        }
    }

    // ---- cross-wave reduce via canonical LDS layout (one barrier pair) ----
    __syncthreads();
    {
        const int col = lane & 31;
        const int rhi = (lane >> 5) << 2;
        #pragma unroll
        for (int r = 0; r < 16; ++r) {
            const int row = (r & 3) + ((r >> 2) << 3) + rhi;   // verified C/D mapping
            u.red[wv * TBL + row * 32 + col] = acc[r];
        }
    }
    __syncthreads();

    // ---- atomic combine (live cells only), device-scope ----
    {
        float* stbl = sums + (size_t)(blockIdx.x & (NREP - 1)) * TBL;
        #pragma unroll
        for (int q = 0; q < TBL / TPB; ++q) {
            const int cell = q * TPB + tid;
            const float v = u.red[cell] + u.red[TBL + cell]
                          + u.red[2 * TBL + cell] + u.red[3 * TBL + cell];
            const int row = cell >> 5, col = cell & 31;
            if (row < K && col < G) atomicAdd(&stbl[cell], v);
        }
    }
    __syncthreads();   // drains vmcnt -> this block's atomics globally performed

    int* cnt = (int*)(sums + SUMS_FLOATS);
    if (tid == 0) {
        const int done = __hip_atomic_fetch_add(cnt, 1, __ATOMIC_ACQ_REL,
                                                __HIP_MEMORY_SCOPE_AGENT);
        last_flag = (done == NBLK - 1) ? 1 : 0;
    }
    __syncthreads();
    if (!last_flag) return;

    // ---- last block: RELAXED pipelined loads (counter RMW was the acquire) ----
    for (int cell = tid; cell < TBL; cell += TPB) {
        float v = 0.f;
        #pragma unroll
        for (int r = 0; r < NREP; ++r)
            v += __hip_atomic_load(&sums[(size_t)r * TBL + cell], __ATOMIC_RELAXED,
                                   __HIP_MEMORY_SCOPE_AGENT);
        u.red[cell] = v;
    }
    __syncthreads();

    if (tid < K) {
        const int GG = (G < 32) ? G : 32;
        float bv; int bg = 0;
        if (GG > 0) {
            bv = u.red[tid * 32];
            for (int g = 1; g < GG; ++g) {
                const float v = u.red[tid * 32 + g];
                if (v > bv) { bv = v; bg = g; }   // strict '>' keeps first index
            }
        }
        out[tid] = bg;
    }
}

extern "C" void kernel_launch(void* const* d_in, const int* in_sizes, int n_in,
                              void* d_out, int out_size, void* d_ws, size_t ws_size,
                              hipStream_t stream) {
    const float* seg = (const float*)d_in[0];
    // d_in[1] (prob) does not affect the reference output
    const int* gt  = (const int*)d_in[2];
    const int* gpn = (const int*)d_in[3];

    const int N = in_sizes[1];              // prob is (N,1)
    const int K = in_sizes[0] / N;          // 21
    const int GROWS = in_sizes[2] / N;      // 21
    const int NGROUP = (N + 63) >> 6;       // 4800 64-px groups

    int NBLK = 600;                         // 2400 waves -> 2 groups/wave
    const int minb = (NGROUP + 3) >> 2;
    if (NBLK > minb) NBLK = minb;
    if (NBLK < 1) NBLK = 1;

    // zero replica tables + counter every call (32 KB + 4 B of d_ws)
    hipMemsetAsync(d_ws, 0, SUMS_FLOATS * sizeof(float) + sizeof(int), stream);

    msk_wave<<<NBLK, TPB, 0, stream>>>(seg, gt, gpn, (float*)d_ws, (int*)d_out,
                                       N, K, GROWS, NGROUP, NBLK);
}

// Round 9
// 25.689 us; speedup vs baseline: 2.4110x; 1.4749x over previous
//
#include <hip/hip_runtime.h>

#define EPSF 1e-6f
#define TPB 256
#define KMAXC 21           // seg channels (K = 21)
#define NGR 21             // gt rows staged
#define RW 72              // bf16 row stride per wave slice (144 B; 16B-aligned frags)
#define SLICE (KMAXC * RW) // 1512 bf16 per matrix per wave
#define TBL 1024           // 32x32 cells per replica table
#define NREP 8             // replicated atomic tables
#define SUMS_FLOATS (NREP * TBL)   // 8192 floats = 32 KB

typedef float  f32x4  __attribute__((ext_vector_type(4)));
typedef float  f32x16 __attribute__((ext_vector_type(16)));
typedef __bf16 bf16x8 __attribute__((ext_vector_type(8)));
typedef __bf16 bf16x4 __attribute__((ext_vector_type(4)));

struct GroupRegs { f32x4 s[6]; int4 g[6]; };

// issue all 12 vector loads for one 64-pixel group (stay in flight together)
__device__ __forceinline__ void issue_loads(const float* __restrict__ seg,
                                            const int* __restrict__ gt,
                                            int N, int GROWS, int p0, int lane,
                                            GroupRegs& r) {
    const f32x4* s4 = (const f32x4*)(seg + (size_t)p0 * KMAXC);
    #pragma unroll
    for (int q = 0; q < 6; ++q) {
        const int i4 = lane + (q << 6);            // f32x4 idx in [0,336)
        f32x4 v = {0.5f, 0.5f, 0.5f, 0.5f};
        if (i4 < 336) v = s4[i4];
        r.s[q] = v;
    }
    #pragma unroll
    for (int q = 0; q < 6; ++q) {
        const int i4 = lane + (q << 6);
        int4 gv = {0, 0, 0, 0};
        if (i4 < 336) {
            int row = i4 >> 4;                     // 0..20 (16 int4 per row)
            row = (row < GROWS) ? row : (GROWS - 1);
            gv = *(const int4*)(gt + (size_t)row * N + p0 + ((i4 & 15) << 2));
        }
        r.g[q] = gv;
    }
}

// log-odds + bf16 scatter to this wave's LDS slice
__device__ __forceinline__ void scatter_group(__bf16* dl, __bf16* ml, int lane,
                                              const GroupRegs& r) {
    #pragma unroll
    for (int q = 0; q < 6; ++q) {
        const int i4 = lane + (q << 6);
        if (i4 < 336) {
            const int lin = i4 << 2;
            int pix = lin / KMAXC;
            int k   = lin - pix * KMAXC;
            #pragma unroll
            for (int c = 0; c < 4; ++c) {
                const float s = r.s[q][c];
                const float dd = __log2f(s + EPSF) - __log2f(1.0f - s + EPSF);
                dl[k * RW + pix] = (__bf16)dd;
                if (++k == KMAXC) { k = 0; ++pix; }
            }
            const int row = i4 >> 4;
            bf16x4 mv;
            mv[0] = (__bf16)(float)(r.g[q].x != 0);
            mv[1] = (__bf16)(float)(r.g[q].y != 0);
            mv[2] = (__bf16)(float)(r.g[q].z != 0);
            mv[3] = (__bf16)(float)(r.g[q].w != 0);
            *(bf16x4*)(ml + row * RW + ((i4 & 15) << 2)) = mv;
        }
    }
}

// 4x MFMA over one 64-pixel group (K-dim = pixels)
__device__ __forceinline__ void mfma_group(const __bf16* dl, const __bf16* ml,
                                           int lane, int K, f32x16& acc) {
    const int r31  = lane & 31;
    const int rowA = (r31 < K)   ? r31 : (K - 1);   // clamp: dup rows discarded
    const int rowB = (r31 < NGR) ? r31 : (NGR - 1);
    const int off  = (lane >> 5) << 3;
    const __bf16* pa = dl + rowA * RW + off;
    const __bf16* pb = ml + rowB * RW + off;
    #pragma unroll
    for (int i = 0; i < 4; ++i) {
        const bf16x8 af = *(const bf16x8*)(pa + i * 16);
        const bf16x8 bf = *(const bf16x8*)(pb + i * 16);
        acc = __builtin_amdgcn_mfma_f32_32x32x16_bf16(af, bf, acc, 0, 0, 0);
    }
}

// generic per-element path (tail group / odd K)
__device__ __forceinline__ void generic_group(const float* __restrict__ seg,
                                              const int* __restrict__ gt,
                                              __bf16* dl, __bf16* ml, int lane,
                                              int N, int K, int GROWS, int p0) {
    for (int i = lane; i < K * 64; i += 64) {
        const int pix = i / K, k = i - pix * K;
        const float s = (p0 + pix < N) ? seg[(size_t)(p0 + pix) * K + k] : 0.5f;
        const float dd = __log2f(s + EPSF) - __log2f(1.0f - s + EPSF);
        if (k < KMAXC) dl[k * RW + pix] = (__bf16)dd;   // s=0.5 -> d=0 (inert)
    }
    for (int i = lane; i < NGR * 64; i += 64) {
        const int row = i >> 6, c = i & 63;
        int val = 0;
        if (row < GROWS && p0 + c < N) val = (gt[(size_t)row * N + p0 + c] != 0);
        ml[row * RW + c] = (__bf16)(float)val;
    }
}

// K0: zero the replica tables (agent-scope stores -> visible to K1's RMWs)
__global__ __launch_bounds__(TPB) void msk_zero(float* __restrict__ sums) {
    const int idx = blockIdx.x * TPB + threadIdx.x;
    if (idx < SUMS_FLOATS)
        __hip_atomic_store(&sums[idx], 0.0f, __ATOMIC_RELAXED,
                           __HIP_MEMORY_SCOPE_AGENT);
}

// K1: A[k,g] = sum_n d[k,n]*gi[g,n]; wave-private, no cross-block sync.
__global__ __launch_bounds__(TPB) void msk_main(
    const float* __restrict__ seg,   // (N, K) row-major
    const int* __restrict__ gt,      // (GROWS, N) row-major
    const int* __restrict__ gpn,     // scalar gt_plane_num
    float* __restrict__ sums,        // NREP*[TBL] f32 replica tables
    int N, int K, int GROWS, int NGROUP, int NBLK)
{
    const int G = *gpn;
    const int tid  = threadIdx.x;
    const int lane = tid & 63;
    const int wv   = tid >> 6;

    __shared__ union {
        __bf16 stage[4][2][SLICE];   // [wave][0=d rows [k][px], 1=mask rows [g][px]]
        float  red[4 * TBL];
    } u;

    f32x16 acc = {};
    __bf16* dl = u.stage[wv][0];
    __bf16* ml = u.stage[wv][1];

    const int W  = NBLK * 4;
    const int gw = (int)blockIdx.x * 4 + wv;

    if (K == KMAXC) {
        const int g0 = gw, g1 = gw + W;
        const bool f0 = (g0 < NGROUP) && ((g0 << 6) + 64 <= N);
        const bool f1 = (g1 < NGROUP) && ((g1 << 6) + 64 <= N);
        GroupRegs r0, r1;
        // ---- 2-deep pipeline: 24 loads in flight before any compute ----
        if (f0) issue_loads(seg, gt, N, GROWS, g0 << 6, lane, r0);
        if (f1) issue_loads(seg, gt, N, GROWS, g1 << 6, lane, r1);
        if (f0) { scatter_group(dl, ml, lane, r0); mfma_group(dl, ml, lane, K, acc); }
        if (f1) { scatter_group(dl, ml, lane, r1); mfma_group(dl, ml, lane, K, acc); }
        // partial groups not covered by the fast path
        if (g0 < NGROUP && !f0) {
            generic_group(seg, gt, dl, ml, lane, N, K, GROWS, g0 << 6);
            mfma_group(dl, ml, lane, K, acc);
        }
        if (g1 < NGROUP && !f1) {
            generic_group(seg, gt, dl, ml, lane, N, K, GROWS, g1 << 6);
            mfma_group(dl, ml, lane, K, acc);
        }
        // any groups beyond 2 per wave
        for (int gid = gw + 2 * W; gid < NGROUP; gid += W) {
            const int p0 = gid << 6;
            if (p0 + 64 <= N) {
                GroupRegs r;
                issue_loads(seg, gt, N, GROWS, p0, lane, r);
                scatter_group(dl, ml, lane, r);
            } else {
                generic_group(seg, gt, dl, ml, lane, N, K, GROWS, p0);
            }
            mfma_group(dl, ml, lane, K, acc);
        }
    } else {
        for (int gid = gw; gid < NGROUP; gid += W) {
            generic_group(seg, gt, dl, ml, lane, N, K, GROWS, gid << 6);
            mfma_group(dl, ml, lane, K, acc);
        }
    }

    // ---- cross-wave reduce via canonical LDS layout ----
    __syncthreads();
    {
        const int col = lane & 31;
        const int rhi = (lane >> 5) << 2;
        #pragma unroll
        for (int r = 0; r < 16; ++r) {
            const int row = (r & 3) + ((r >> 2) << 3) + rhi;   // verified C/D mapping
            u.red[wv * TBL + row * 32 + col] = acc[r];
        }
    }
    __syncthreads();

    // ---- atomic combine into replica table (live cells only) ----
    {
        float* stbl = sums + (size_t)(blockIdx.x & (NREP - 1)) * TBL;
        #pragma unroll
        for (int q = 0; q < TBL / TPB; ++q) {
            const int cell = q * TPB + tid;
            const float v = u.red[cell] + u.red[TBL + cell]
                          + u.red[2 * TBL + cell] + u.red[3 * TBL + cell];
            const int row = cell >> 5, col = cell & 31;
            if (row < K && col < G) atomicAdd(&stbl[cell], v);
        }
    }
}

// K2: reduce replica tables, first-index argmax per k row, write out
__global__ __launch_bounds__(TPB) void msk_final(
    const float* __restrict__ sums,
    const int* __restrict__ gpn,
    int* __restrict__ out,
    int K)
{
    const int G = *gpn;
    const int tid = threadIdx.x;
    __shared__ float A[KMAXC * 32 + 32];

    const int NC = K * 32;   // live rows x 32 cols (dead cols are exact zeros)
    for (int c = tid; c < NC; c += TPB) {
        float v = 0.f;
        #pragma unroll
        for (int r = 0; r < NREP; ++r)
            v += __hip_atomic_load(&sums[(size_t)r * TBL + c], __ATOMIC_RELAXED,
                                   __HIP_MEMORY_SCOPE_AGENT);
        A[c] = v;
    }
    __syncthreads();

    if (tid < K) {
        const int GG = (G < 32) ? G : 32;
        float bv; int bg = 0;
        if (GG > 0) {
            bv = A[tid * 32];
            for (int g = 1; g < GG; ++g) {
                const float v = A[tid * 32 + g];
                if (v > bv) { bv = v; bg = g; }   // strict '>' keeps first index
            }
        }
        out[tid] = bg;
    }
}

extern "C" void kernel_launch(void* const* d_in, const int* in_sizes, int n_in,
                              void* d_out, int out_size, void* d_ws, size_t ws_size,
                              hipStream_t stream) {
    const float* seg = (const float*)d_in[0];
    // d_in[1] (prob) does not affect the reference output
    const int* gt  = (const int*)d_in[2];
    const int* gpn = (const int*)d_in[3];

    const int N = in_sizes[1];              // prob is (N,1)
    const int K = in_sizes[0] / N;          // 21
    const int GROWS = in_sizes[2] / N;      // 21
    const int NGROUP = (N + 63) >> 6;       // 4800 64-px groups

    int NBLK = 600;                         // 2400 waves -> exactly 2 groups/wave
    const int minb = (NGROUP + 3) >> 2;
    if (NBLK > minb) NBLK = minb;
    if (NBLK < 1) NBLK = 1;

    msk_zero <<<SUMS_FLOATS / TPB, TPB, 0, stream>>>((float*)d_ws);
    msk_main <<<NBLK, TPB, 0, stream>>>(seg, gt, gpn, (float*)d_ws,
                                        N, K, GROWS, NGROUP, NBLK);
    msk_final<<<1, TPB, 0, stream>>>((const float*)d_ws, gpn, (int*)d_out, K);
}

// Round 10
// 25.214 us; speedup vs baseline: 2.4564x; 1.0188x over previous
//
#include <hip/hip_runtime.h>

#define EPSF 1e-6f
#define TPB 256
#define KMAXC 21           // seg channels (K = 21)
#define NGR 21             // gt rows staged
#define RW 72              // bf16 row stride per wave slice (144 B; 16B-aligned frags)
#define SLICE (KMAXC * RW) // 1512 bf16 per matrix per wave
#define TBL 1024           // 32x32 cells per per-block table (4 KB stride)
#define MAXBLK 1200

typedef float  f32x4  __attribute__((ext_vector_type(4)));
typedef float  f32x16 __attribute__((ext_vector_type(16)));
typedef __bf16 bf16x8 __attribute__((ext_vector_type(8)));
typedef __bf16 bf16x4 __attribute__((ext_vector_type(4)));

struct GroupRegs { f32x4 s[6]; int4 g[6]; };

// issue all 12 vector loads for one 64-pixel group (stay in flight together)
__device__ __forceinline__ void issue_loads(const float* __restrict__ seg,
                                            const int* __restrict__ gt,
                                            int N, int GROWS, int p0, int lane,
                                            GroupRegs& r) {
    const f32x4* s4 = (const f32x4*)(seg + (size_t)p0 * KMAXC);
    #pragma unroll
    for (int q = 0; q < 6; ++q) {
        const int i4 = lane + (q << 6);            // f32x4 idx in [0,336)
        f32x4 v = {0.5f, 0.5f, 0.5f, 0.5f};
        if (i4 < 336) v = s4[i4];
        r.s[q] = v;
    }
    #pragma unroll
    for (int q = 0; q < 6; ++q) {
        const int i4 = lane + (q << 6);
        int4 gv = {0, 0, 0, 0};
        if (i4 < 336) {
            int row = i4 >> 4;                     // 0..20 (16 int4 per row)
            row = (row < GROWS) ? row : (GROWS - 1);
            gv = *(const int4*)(gt + (size_t)row * N + p0 + ((i4 & 15) << 2));
        }
        r.g[q] = gv;
    }
}

// log-odds + bf16 scatter to this wave's LDS slice
__device__ __forceinline__ void scatter_group(__bf16* dl, __bf16* ml, int lane,
                                              const GroupRegs& r) {
    #pragma unroll
    for (int q = 0; q < 6; ++q) {
        const int i4 = lane + (q << 6);
        if (i4 < 336) {
            const int lin = i4 << 2;
            int pix = lin / KMAXC;
            int k   = lin - pix * KMAXC;
            #pragma unroll
            for (int c = 0; c < 4; ++c) {
                const float s = r.s[q][c];
                const float dd = __log2f(s + EPSF) - __log2f(1.0f - s + EPSF);
                dl[k * RW + pix] = (__bf16)dd;
                if (++k == KMAXC) { k = 0; ++pix; }
            }
            const int row = i4 >> 4;
            bf16x4 mv;
            mv[0] = (__bf16)(float)(r.g[q].x != 0);
            mv[1] = (__bf16)(float)(r.g[q].y != 0);
            mv[2] = (__bf16)(float)(r.g[q].z != 0);
            mv[3] = (__bf16)(float)(r.g[q].w != 0);
            *(bf16x4*)(ml + row * RW + ((i4 & 15) << 2)) = mv;
        }
    }
}

// 4x MFMA over one 64-pixel group (K-dim = pixels)
__device__ __forceinline__ void mfma_group(const __bf16* dl, const __bf16* ml,
                                           int lane, int K, f32x16& acc) {
    const int r31  = lane & 31;
    const int rowA = (r31 < K)   ? r31 : (K - 1);   // clamp: dup rows discarded
    const int rowB = (r31 < NGR) ? r31 : (NGR - 1);
    const int off  = (lane >> 5) << 3;
    const __bf16* pa = dl + rowA * RW + off;
    const __bf16* pb = ml + rowB * RW + off;
    #pragma unroll
    for (int i = 0; i < 4; ++i) {
        const bf16x8 af = *(const bf16x8*)(pa + i * 16);
        const bf16x8 bf = *(const bf16x8*)(pb + i * 16);
        acc = __builtin_amdgcn_mfma_f32_32x32x16_bf16(af, bf, acc, 0, 0, 0);
    }
}

// generic per-element path (tail group / odd K)
__device__ __forceinline__ void generic_group(const float* __restrict__ seg,
                                              const int* __restrict__ gt,
                                              __bf16* dl, __bf16* ml, int lane,
                                              int N, int K, int GROWS, int p0) {
    for (int i = lane; i < K * 64; i += 64) {
        const int pix = i / K, k = i - pix * K;
        const float s = (p0 + pix < N) ? seg[(size_t)(p0 + pix) * K + k] : 0.5f;
        const float dd = __log2f(s + EPSF) - __log2f(1.0f - s + EPSF);
        if (k < KMAXC) dl[k * RW + pix] = (__bf16)dd;   // s=0.5 -> d=0 (inert)
    }
    for (int i = lane; i < NGR * 64; i += 64) {
        const int row = i >> 6, c = i & 63;
        int val = 0;
        if (row < GROWS && p0 + c < N) val = (gt[(size_t)row * N + p0 + c] != 0);
        ml[row * RW + c] = (__bf16)(float)val;
    }
}

// K1: A[k,g] = sum_n d[k,n]*gi[g,n]; wave-private; per-block private output
// table (no atom-RMW, no zero-init needed: every read cell written each call).
__global__ __launch_bounds__(TPB) void msk_main(
    const float* __restrict__ seg,   // (N, K) row-major
    const int* __restrict__ gt,      // (GROWS, N) row-major
    float* __restrict__ sums,        // NBLK x [TBL] f32 per-block tables
    int N, int K, int GROWS, int NGROUP, int NBLK)
{
    const int tid  = threadIdx.x;
    const int lane = tid & 63;
    const int wv   = tid >> 6;

    __shared__ union {
        __bf16 stage[4][2][SLICE];   // [wave][0=d rows [k][px], 1=mask rows [g][px]]
        float  red[4 * TBL];
    } u;

    f32x16 acc = {};
    __bf16* dl = u.stage[wv][0];
    __bf16* ml = u.stage[wv][1];

    const int W  = NBLK * 4;
    const int gw = (int)blockIdx.x * 4 + wv;

    if (K == KMAXC) {
        const int g0 = gw, g1 = gw + W;
        const bool f0 = (g0 < NGROUP) && ((g0 << 6) + 64 <= N);
        const bool f1 = (g1 < NGROUP) && ((g1 << 6) + 64 <= N);
        GroupRegs r0, r1;
        if (f0) issue_loads(seg, gt, N, GROWS, g0 << 6, lane, r0);
        if (f1) issue_loads(seg, gt, N, GROWS, g1 << 6, lane, r1);
        if (f0) { scatter_group(dl, ml, lane, r0); mfma_group(dl, ml, lane, K, acc); }
        if (f1) { scatter_group(dl, ml, lane, r1); mfma_group(dl, ml, lane, K, acc); }
        if (g0 < NGROUP && !f0) {
            generic_group(seg, gt, dl, ml, lane, N, K, GROWS, g0 << 6);
            mfma_group(dl, ml, lane, K, acc);
        }
        if (g1 < NGROUP && !f1) {
            generic_group(seg, gt, dl, ml, lane, N, K, GROWS, g1 << 6);
            mfma_group(dl, ml, lane, K, acc);
        }
        for (int gid = gw + 2 * W; gid < NGROUP; gid += W) {
            const int p0 = gid << 6;
            if (p0 + 64 <= N) {
                GroupRegs r;
                issue_loads(seg, gt, N, GROWS, p0, lane, r);
                scatter_group(dl, ml, lane, r);
            } else {
                generic_group(seg, gt, dl, ml, lane, N, K, GROWS, p0);
            }
            mfma_group(dl, ml, lane, K, acc);
        }
    } else {
        for (int gid = gw; gid < NGROUP; gid += W) {
            generic_group(seg, gt, dl, ml, lane, N, K, GROWS, gid << 6);
            mfma_group(dl, ml, lane, K, acc);
        }
    }

    // ---- cross-wave reduce via canonical LDS layout ----
    __syncthreads();
    {
        const int col = lane & 31;
        const int rhi = (lane >> 5) << 2;
        #pragma unroll
        for (int r = 0; r < 16; ++r) {
            const int row = (r & 3) + ((r >> 2) << 3) + rhi;   // verified C/D mapping
            u.red[wv * TBL + row * 32 + col] = acc[r];
        }
    }
    __syncthreads();

    // ---- private table write: relaxed agent-scope atomic stores (coherent
    //      point; plain stores proved unsafe cross-kernel under graph replay) ----
    {
        float* stbl = sums + (size_t)blockIdx.x * TBL;
        #pragma unroll
        for (int q = 0; q < TBL / TPB; ++q) {
            const int cell = q * TPB + tid;
            const float v = u.red[cell] + u.red[TBL + cell]
                          + u.red[2 * TBL + cell] + u.red[3 * TBL + cell];
            __hip_atomic_store(&stbl[cell], v, __ATOMIC_RELAXED,
                               __HIP_MEMORY_SCOPE_AGENT);
        }
    }
}

// K2: block k reduces its row across all NBLK tables, first-index argmax.
__global__ __launch_bounds__(512) void msk_final(
    const float* __restrict__ sums,
    const int* __restrict__ gpn,
    int* __restrict__ out,
    int K, int NBLK)
{
    const int G = *gpn;
    const int k = blockIdx.x;
    const int tid = threadIdx.x;
    const int col = tid & 31;
    const int grp = tid >> 5;            // 16 table-groups

    // 4-way interleaved relaxed atomic loads (coalesced 128 B per lane-group)
    float v0 = 0.f, v1 = 0.f, v2 = 0.f, v3 = 0.f;
    const size_t base = (size_t)k * 32 + col;
    int tbl = grp;
    for (; tbl + 48 < NBLK; tbl += 64) {
        v0 += __hip_atomic_load(&sums[(size_t)(tbl     ) * TBL + base],
                                __ATOMIC_RELAXED, __HIP_MEMORY_SCOPE_AGENT);
        v1 += __hip_atomic_load(&sums[(size_t)(tbl + 16) * TBL + base],
                                __ATOMIC_RELAXED, __HIP_MEMORY_SCOPE_AGENT);
        v2 += __hip_atomic_load(&sums[(size_t)(tbl + 32) * TBL + base],
                                __ATOMIC_RELAXED, __HIP_MEMORY_SCOPE_AGENT);
        v3 += __hip_atomic_load(&sums[(size_t)(tbl + 48) * TBL + base],
                                __ATOMIC_RELAXED, __HIP_MEMORY_SCOPE_AGENT);
    }
    for (; tbl < NBLK; tbl += 16)
        v0 += __hip_atomic_load(&sums[(size_t)tbl * TBL + base],
                                __ATOMIC_RELAXED, __HIP_MEMORY_SCOPE_AGENT);
    const float v = (v0 + v1) + (v2 + v3);

    __shared__ float P[16][33];
    __shared__ float A[32];
    P[grp][col] = v;
    __syncthreads();
    if (tid < 32) {
        float s = 0.f;
        #pragma unroll
        for (int g2 = 0; g2 < 16; ++g2) s += P[g2][tid];
        A[tid] = s;
    }
    __syncthreads();

    if (tid == 0) {
        const int GG = (G < 32) ? G : 32;
        float bv; int bg = 0;
        if (GG > 0) {
            bv = A[0];
            for (int g = 1; g < GG; ++g) {
                const float vv = A[g];
                if (vv > bv) { bv = vv; bg = g; }   // strict '>' keeps first index
            }
        }
        out[k] = bg;
    }
}

extern "C" void kernel_launch(void* const* d_in, const int* in_sizes, int n_in,
                              void* d_out, int out_size, void* d_ws, size_t ws_size,
                              hipStream_t stream) {
    const float* seg = (const float*)d_in[0];
    // d_in[1] (prob) does not affect the reference output
    const int* gt  = (const int*)d_in[2];
    const int* gpn = (const int*)d_in[3];

    const int N = in_sizes[1];              // prob is (N,1)
    const int K = in_sizes[0] / N;          // 21
    const int GROWS = in_sizes[2] / N;      // 21
    const int NGROUP = (N + 63) >> 6;       // 4800 64-px groups

    int NBLK = MAXBLK;                      // 1 group per wave at 1200 blocks
    const int minb = (NGROUP + 3) >> 2;
    if (NBLK > minb) NBLK = minb;
    const long long wcap = (long long)(ws_size / (TBL * sizeof(float)));
    if (NBLK > wcap) NBLK = (int)wcap;      // d_ws budget (observed ~256 MB)
    if (NBLK < 1) NBLK = 1;

    msk_main <<<NBLK, TPB, 0, stream>>>(seg, gt, (float*)d_ws,
                                        N, K, GROWS, NGROUP, NBLK);
    msk_final<<<K, 512, 0, stream>>>((const float*)d_ws, gpn, (int*)d_out,
                                     K, NBLK);
}